// Round 16
// baseline (62.521 us; speedup 1.0000x reference)
//
#include <hip/hip_runtime.h>

constexpr int kN = 4, kC = 19, kH = 512, kW = 512;
constexpr int kHW = kH * kW;                       // 2^18
constexpr int kS = 2048;      // NUM_SUPERPIXEL
constexpr int kSsm = 8192;    // NUM_SMALL
constexpr float kEps = 1e-8f;
constexpr int kSub = 4;       // R15: argmax sub-buckets (k = pixel & 3)

constexpr int kNSC = kN * kS * kC;                 // need_mark domain (155,648)
constexpr int kPixBlocks = kN * kHW / 256;         // 4096 (exact)

// ---- workspace layout (bytes) ----
constexpr size_t OFF_AMAX = 0;                                   // u64[N*S*C][kSub]
constexpr size_t SZ_AMAX  = (size_t)kNSC * kSub * 8;             // 4.98 MB
constexpr size_t OFF_MULT = OFF_AMAX + SZ_AMAX;                  // u32[N*Ssm*C] multiplicity
constexpr size_t SZ_MULT  = (size_t)kN * kSsm * kC * 4;
constexpr size_t OFF_NM   = OFF_MULT + SZ_MULT;                  // u32[N*Ssm] needed-channel bits
constexpr size_t SZ_NM    = (size_t)kN * kSsm * 4;
constexpr size_t ZERO_BYTES = OFF_NM + SZ_NM;                    // zeroed region (16B-multiple)
constexpr size_t ZERO_CHUNKS = ZERO_BYTES / 16;
constexpr size_t OFF_TM   = ZERO_BYTES;                          // u32[N*S] target channel bitmask
constexpr size_t SZ_TM    = (size_t)kN * kS * 4;
constexpr size_t OFF_PL   = OFF_TM + SZ_TM;                      // f32[kPixBlocks] loss partials
constexpr size_t SZ_PL    = (size_t)kPixBlocks * 4;
constexpr size_t OFF_PN   = OFF_PL + SZ_PL;                      // i32[kPixBlocks] nv partials
constexpr size_t SZ_PN    = (size_t)kPixBlocks * 4;
constexpr size_t WS_TOTAL = OFF_PN + SZ_PN;                      // ~7.7 MB (R12-proven size)

// Fused: zero the accumulator region + build tmask.
__global__ void init_kernel(const float* __restrict__ targets,
                            unsigned* __restrict__ tmask,
                            ulong2* __restrict__ ws) {
    size_t gid = (size_t)blockIdx.x * blockDim.x + threadIdx.x;
    size_t stride = (size_t)gridDim.x * blockDim.x;
    for (size_t i = gid; i < ZERO_CHUNKS; i += stride)
        ws[i] = ulong2{0ULL, 0ULL};
    if (gid < (size_t)kN * kS) {
        const float* t = targets + gid * (kC + 1);
        unsigned m = 0;
#pragma unroll
        for (int c = 0; c < kC; ++c)
            if (t[c] > 0.f) m |= (1u << c);
        tmask[gid] = m;
    }
}

// Weak branch (R10 body): per-(segment,channel) lexicographic argmax via
// fire-and-forget u64 atomicMax of (float_bits(v)<<32)|~pixel.
// R15: 4 sub-buckets per (s,c) slot, k = pixel&3. R13/R14 isolated weak's
// dominant cost as SAME-ADDRESS atomic serialization (~100 atomics/slot
// x ~13ns RMW chains): sub-buckets cut chains 4x; need_mark max-reduces
// the 4 sub-slots (exact, deterministic).
__global__ void weak_argmax_kernel(const float* __restrict__ logits,
                                   const unsigned char* __restrict__ mask,
                                   const int* __restrict__ seg,
                                   const unsigned* __restrict__ tmask,
                                   unsigned long long* __restrict__ amax4) {
    int gid = blockIdx.x * blockDim.x + threadIdx.x;
    if (!mask[gid]) return;
    int n = gid >> 18;
    int p = gid & (kHW - 1);
    int s = seg[gid];
    unsigned tm = tmask[n * kS + s];
    if (!tm) return;

    const float* base = logits + (size_t)n * kC * kHW + p;
    float sum = 0.f;
#pragma unroll
    for (int c = 0; c < kC; ++c)
        sum += __expf(base[(size_t)c * kHW]);
    float inv = 1.f / sum;

    unsigned long long lowbits = (unsigned int)(~(unsigned int)p);
    unsigned long long* dst =
        amax4 + (((size_t)n * kS + s) * kC) * kSub + (p & (kSub - 1));
    unsigned bits = tm;
    while (bits) {
        int c = __ffs(bits) - 1;
        bits &= bits - 1;
        float v = __expf(base[(size_t)c * kHW]) * inv;  // L1-hot reload
        unsigned long long key =
            ((unsigned long long)__float_as_uint(v) << 32) | lowbits;
        atomicMax(&dst[c * kSub], key);
    }
}

// For each live (n,s,c) pair: max-reduce the 4 sub-buckets, then record
// needed-channel bit and multiplicity (R10 summation-order swap).
__global__ void need_mark_kernel(const unsigned long long* __restrict__ amax4,
                                 const unsigned* __restrict__ tmask,
                                 const int* __restrict__ small_w,
                                 unsigned* __restrict__ needmask,
                                 unsigned* __restrict__ mult) {
    int gid = blockIdx.x * blockDim.x + threadIdx.x;
    if (gid >= kNSC) return;
    int n = gid / (kS * kC);
    int rem = gid - n * (kS * kC);
    int s = rem / kC;
    int c = rem - s * kC;
    if (!((tmask[n * kS + s] >> c) & 1u)) return;
    const unsigned long long* sub = amax4 + (size_t)gid * kSub;
    unsigned long long packed = sub[0];
    packed = max(packed, sub[1]);
    packed = max(packed, sub[2]);
    packed = max(packed, sub[3]);
    if (packed == 0ULL) return;  // empty segment (has_pixel == false)
    unsigned pix = ~(unsigned)(packed & 0xFFFFFFFFULL);
    int sel = small_w[(size_t)n * kHW + pix];
    atomicOr(&needmask[n * kSsm + sel], 1u << c);
    atomicAdd(&mult[((size_t)n * kSsm + sel) * kC + c], 1u);
}

// Strong branch (R10, unchanged): softmax + mult-weighted nll,
// block-reduced to one (loss, nv) partial per block.
__global__ void strong_loss_kernel(const float* __restrict__ logits,
                                   const unsigned char* __restrict__ mask,
                                   const int* __restrict__ seg,
                                   const unsigned* __restrict__ needmask,
                                   const unsigned* __restrict__ mult,
                                   float* __restrict__ ploss,
                                   int* __restrict__ pnv) {
    __shared__ float sLoss[4];
    __shared__ int sNv[4];
    int gid = blockIdx.x * blockDim.x + threadIdx.x;  // exact grid
    float loss = 0.f;
    int nvv = 0;
    if (mask[gid]) {
        int n = gid >> 18;
        int p = gid & (kHW - 1);
        int ss = seg[gid];
        unsigned nm = needmask[n * kSsm + ss];
        if (nm) {
            const float* base = logits + (size_t)n * kC * kHW + p;
            float sum = 0.f;
#pragma unroll
            for (int c = 0; c < kC; ++c)
                sum += __expf(base[(size_t)c * kHW]);
            float inv = 1.f / sum;

            const unsigned* row = mult + ((size_t)n * kSsm + ss) * kC;
            unsigned bits = nm;
            while (bits) {
                int c = __ffs(bits) - 1;
                bits &= bits - 1;
                unsigned m = row[c];                            // L2-resident
                float v = __expf(base[(size_t)c * kHW]) * inv;  // L1-hot reload
                loss += (float)m * (-__logf(v + kEps));
                nvv += (int)m;
            }
        }
    }
    // all threads reach here (no early returns) — block reduction
#pragma unroll
    for (int off = 32; off > 0; off >>= 1) {
        loss += __shfl_down(loss, off);
        nvv += __shfl_down(nvv, off);
    }
    int wave = threadIdx.x >> 6;
    if ((threadIdx.x & 63) == 0) {
        sLoss[wave] = loss;
        sNv[wave] = nvv;
    }
    __syncthreads();
    if (threadIdx.x == 0) {
        ploss[blockIdx.x] = sLoss[0] + sLoss[1] + sLoss[2] + sLoss[3];
        pnv[blockIdx.x]   = sNv[0] + sNv[1] + sNv[2] + sNv[3];
    }
}

// Single-block reduction of the 4096 per-block partials + final divide.
__global__ void finalize_kernel(const float* __restrict__ ploss,
                                const int* __restrict__ pnv,
                                float* __restrict__ out) {
    __shared__ float sLoss[4];
    __shared__ int sNv[4];
    float lv = 0.f;
    int nvv = 0;
    for (int i = threadIdx.x; i < kPixBlocks; i += 256) {
        lv += ploss[i];
        nvv += pnv[i];
    }
#pragma unroll
    for (int off = 32; off > 0; off >>= 1) {
        lv += __shfl_down(lv, off);
        nvv += __shfl_down(nvv, off);
    }
    int wave = threadIdx.x >> 6;
    if ((threadIdx.x & 63) == 0) {
        sLoss[wave] = lv;
        sNv[wave] = nvv;
    }
    __syncthreads();
    if (threadIdx.x == 0) {
        float tl = sLoss[0] + sLoss[1] + sLoss[2] + sLoss[3];
        int tn = sNv[0] + sNv[1] + sNv[2] + sNv[3];
        out[0] = tl / (float)(1 + tn);
    }
}

extern "C" void kernel_launch(void* const* d_in, const int* in_sizes, int n_in,
                              void* d_out, int out_size, void* d_ws, size_t ws_size,
                              hipStream_t stream) {
    const float* inputs            = (const float*)d_in[0];
    const float* inputs_weak       = (const float*)d_in[1];
    const float* targets           = (const float*)d_in[2];
    const unsigned char* spmasks      = (const unsigned char*)d_in[3];
    const unsigned char* spmasks_weak = (const unsigned char*)d_in[4];
    // d_in[5] superpixels: unused by the reference
    const int* superpixels_weak    = (const int*)d_in[6];
    const int* superpixel_smalls   = (const int*)d_in[7];
    const int* spx_smalls_weak     = (const int*)d_in[8];
    float* out = (float*)d_out;

    unsigned long long* amax4 = (unsigned long long*)((char*)d_ws + OFF_AMAX);
    unsigned* mult           = (unsigned*)((char*)d_ws + OFF_MULT);
    unsigned* needmask       = (unsigned*)((char*)d_ws + OFF_NM);
    unsigned* tmask          = (unsigned*)((char*)d_ws + OFF_TM);
    float* ploss             = (float*)((char*)d_ws + OFF_PL);
    int* pnv                 = (int*)((char*)d_ws + OFF_PN);

    init_kernel<<<2048, 256, 0, stream>>>(targets, tmask, (ulong2*)d_ws);
    weak_argmax_kernel<<<kPixBlocks, 256, 0, stream>>>(inputs_weak, spmasks_weak,
                                                       superpixels_weak, tmask,
                                                       amax4);
    need_mark_kernel<<<(kNSC + 255) / 256, 256, 0, stream>>>(amax4, tmask,
                                                             spx_smalls_weak,
                                                             needmask, mult);
    strong_loss_kernel<<<kPixBlocks, 256, 0, stream>>>(inputs, spmasks,
                                                       superpixel_smalls,
                                                       needmask, mult, ploss, pnv);
    finalize_kernel<<<1, 256, 0, stream>>>(ploss, pnv, out);
}